// Round 15
// baseline (68.247 us; speedup 1.0000x reference)
//
#include <hip/hip_runtime.h>
#include <hip/hip_bf16.h>

// Problem constants (S4Layer: T=4096, B=16, D=128, S=256)
#define T_  4096
#define B_  16
#define D_  128
#define S_  256
#define WND 64             // chunk length = GEMM t-tile
#define C4  (T_/WND)       // 64 chunks

using bf8   = __attribute__((ext_vector_type(8))) short;   // 8 bf16 (4 VGPRs)
using f32x4 = __attribute__((ext_vector_type(4))) float;   // MFMA acc

__device__ inline float bfbits(unsigned h) {               // low 16 bits = bf16
    return __builtin_bit_cast(float, h << 16);
}

// ub fragment-native layout, byte offset of fragment (c,b,w,j,i), lane:
//   ((((c*B+b)*4+w)*4+j)*4+i)*512 + lane*8
// element (t,s): s = w*64+j*16+l15, t = i*16+l4*4+r, lane = l4*16+l15,
// r packed in uint2 (r0 = x.lo, r1 = x.hi, r2 = y.lo, r3 = y.hi).

// ---------------- K1: parameters (hoisted, computed ONCE) -------------------
__global__ __launch_bounds__(256) void k_params(
        const float* __restrict__ lna, const float* __restrict__ bmat,
        const float* __restrict__ ldt,
        float* __restrict__ abar, float* __restrict__ a64,
        __hip_bfloat16* __restrict__ bbar) {
    if (blockIdx.x < 128) {
        int idx = blockIdx.x * 256 + threadIdx.x;   // (s,d)
        int s = idx >> 7;
        float la = fminf(fmaxf(lna[s], -8.f), 4.f);
        float ar = -expf(la);
        float lt = fminf(fmaxf(ldt[s], -8.f), 1.f);
        float dt = expf(lt);
        float xx = dt * ar;
        float ratio = (fabsf(xx) < 1e-6f) ? dt : (expm1f(xx) / ar);
        bbar[idx] = __float2bfloat16(ratio * bmat[idx]);
    } else {
        int s = threadIdx.x;
        float la = fminf(fmaxf(lna[s], -8.f), 4.f);
        float ar = -expf(la);
        float lt = fminf(fmaxf(ldt[s], -8.f), 1.f);
        float dt = expf(lt);
        float ab = expf(dt * ar);
        abar[s] = ab;
        float p = ab;
#pragma unroll
        for (int j = 0; j < 6; ++j) p *= p;     // a^64 by squaring
        a64[s] = p;
    }
}

// ---------------- K2: GEMM + e64 -> ub (fragment-native bf16) --------------
// Block (c,b): 64t x 256s tile. ONE sync; per-(i,j) fragment goes straight
// from acc to a wave-contiguous 512B uint2 store. 16 KiB LDS (A-stage only),
// minimal live registers -> target 8 blocks/CU.
__global__ __launch_bounds__(256, 8) void k_gemm(
        const float* __restrict__ x, const __hip_bfloat16* __restrict__ bbar,
        const float* __restrict__ abar,
        __hip_bfloat16* __restrict__ ub, float* __restrict__ e64) {
    const int c = blockIdx.x, b = blockIdx.y;
    __shared__ char LDS[WND * 256];    // 16 KiB: A-stage [64][128] bf16 swizzled
    const int tid = threadIdx.x, lane = tid & 63, w = tid >> 6;
    const int l15 = lane & 15, l4 = lane >> 4;

    // Stage A: rows t'=0..63 of batch b, fp32 -> bf16, swizzle ^((row&7)<<4)
#pragma unroll
    for (int k = 0; k < 8; ++k) {
        int idx = tid + k * 256;
        int row = idx >> 5, seg = idx & 31;
        float4 v = *(const float4*)(x + ((size_t)(c * WND + row) * B_ + b) * D_ + seg * 4);
        __hip_bfloat162 lo = __float22bfloat162_rn(make_float2(v.x, v.y));
        __hip_bfloat162 hi = __float22bfloat162_rn(make_float2(v.z, v.w));
        uint2 pk = { *(unsigned*)&lo, *(unsigned*)&hi };
        int off = (row * 256 + seg * 8) ^ ((row & 7) << 4);
        *(uint2*)(LDS + off) = pk;
    }
    __syncthreads();

    // Per j (16 s-columns of this wave): bfrag, then 4 fragments i=0..3.
    // Each fragment: 4 MFMA -> cvt -> direct coalesced store + e64 Horner.
    char* fb = (char*)ub + ((((size_t)c * B_ + b) * 4 + w) * 4) * 2048 + lane * 8;
    for (int j = 0; j < 4; ++j) {
        int s = w * 64 + j * 16 + l15;
        bf8 bfrag[4];
#pragma unroll
        for (int kk = 0; kk < 4; ++kk)
            bfrag[kk] = *(const bf8*)((const short*)bbar + s * D_ + kk * 32 + l4 * 8);
        float a  = abar[s];
        float a2 = a * a, a4 = a2 * a2, a8 = a4 * a4, a16 = a8 * a8;
        float lf = (l4 == 0) ? a8 * a4 : (l4 == 1) ? a8 : (l4 == 2) ? a4 : 1.f;
        float e = 0.f;
#pragma unroll
        for (int i = 0; i < 4; ++i) {
            f32x4 acc = {0.f, 0.f, 0.f, 0.f};
#pragma unroll
            for (int kk = 0; kk < 4; ++kk) {
                int tr = i * 16 + l15;
                int off = (tr * 256 + kk * 64 + l4 * 16) ^ ((tr & 7) << 4);
                bf8 af = *(const bf8*)(LDS + off);
                acc = __builtin_amdgcn_mfma_f32_16x16x32_bf16(af, bfrag[kk], acc, 0, 0, 0);
            }
            // pack 4 t-values (RNE, identical to __float2bfloat16 per elem)
            __hip_bfloat162 p0 = __float22bfloat162_rn(make_float2(acc[0], acc[1]));
            __hip_bfloat162 p1 = __float22bfloat162_rn(make_float2(acc[2], acc[3]));
            uint2 pk = { *(unsigned*)&p0, *(unsigned*)&p1 };
            *(uint2*)(fb + (j * 4 + i) * 512) = pk;
            // e64 Horner over bf16-rounded values (t ascending within fragment)
            float inner = bfbits(pk.x & 0xffffu);
            inner = fmaf(inner, a, bfbits(pk.x >> 16));
            inner = fmaf(inner, a, bfbits(pk.y & 0xffffu));
            inner = fmaf(inner, a, bfbits(pk.y >> 16));
            e = fmaf(e, a16, inner);
        }
        e *= lf;
        e += __shfl_xor(e, 16);
        e += __shfl_xor(e, 32);
        if (l4 == 0) e64[((size_t)c * B_ + b) * S_ + s] = e;
    }
}

// ---------------- K3: fused carry + per-chunk scan + out -------------------
// Block (c,b), thread = s. Reads its 64 t-values as 16 uint2 fragments
// (issued upfront, independent); carry via fixed-trip predicated Horner.
__global__ __launch_bounds__(256) void k_scan(
        const __hip_bfloat16* __restrict__ ub, const float* __restrict__ e64,
        const float* __restrict__ abar, const float* __restrict__ a64,
        const float* __restrict__ z0, float* __restrict__ out) {
    const int c = blockIdx.x, b = blockIdx.y, s = threadIdx.x;
    const int w = s >> 6, j = (s >> 4) & 3, l15 = s & 15;

    // preload own fragments: 16 independent 8B loads
    const char* fb = (const char*)ub + ((((size_t)c * B_ + b) * 4 + w) * 4 + j) * 2048
                     + l15 * 8;
    uint2 v[16];
#pragma unroll
    for (int i = 0; i < 4; ++i)
#pragma unroll
        for (int l4 = 0; l4 < 4; ++l4)
            v[i * 4 + l4] = *(const uint2*)(fb + i * 512 + l4 * 128);

    // carry: 64 fixed trips, batch-16 independent loads then predicated fma
    const float a  = abar[s];
    const float aw = a64[s];
    float z = z0[b * S_ + s];
#pragma unroll
    for (int cp0 = 0; cp0 < C4; cp0 += 16) {
        float ev[16];
#pragma unroll
        for (int k = 0; k < 16; ++k)
            ev[k] = e64[((size_t)(cp0 + k) * B_ + b) * S_ + s];
#pragma unroll
        for (int k = 0; k < 16; ++k) {
            float zn = fmaf(aw, z, ev[k]);
            z = (cp0 + k < c) ? zn : z;
        }
    }

    // scan: t = k*4 + r, k = i*4+l4 ascending; coalesced 4B stores (256B/wave)
    float* op = out + ((size_t)(c * WND) * B_ + b) * S_ + s;
    const size_t ostr = (size_t)B_ * S_;
#pragma unroll
    for (int k = 0; k < 16; ++k) {
        uint2 u = v[k];
        z = fmaf(a, z, bfbits(u.x & 0xffffu)); *op = z; op += ostr;
        z = fmaf(a, z, bfbits(u.x >> 16));     *op = z; op += ostr;
        z = fmaf(a, z, bfbits(u.y & 0xffffu)); *op = z; op += ostr;
        z = fmaf(a, z, bfbits(u.y >> 16));     *op = z; op += ostr;
    }
}

extern "C" void kernel_launch(void* const* d_in, const int* in_sizes, int n_in,
                              void* d_out, int out_size, void* d_ws, size_t ws_size,
                              hipStream_t stream) {
    const float* x   = (const float*)d_in[0];  // [T,B,D]
    const float* z0  = (const float*)d_in[1];  // [B,S]
    const float* lna = (const float*)d_in[2];  // [S]
    const float* bm  = (const float*)d_in[3];  // [S,D]
    const float* ldt = (const float*)d_in[4];  // [S]
    float* out = (float*)d_out;

    char* ws = (char*)d_ws;
    float*          abar = (float*)ws;                        // 1 KiB
    float*          a64  = (float*)(ws + 4096);               // 1 KiB
    __hip_bfloat16* bbar = (__hip_bfloat16*)(ws + 8192);      // 64 KiB
    float*          e64  = (float*)(ws + (128 << 10));        // 1 MiB [c][b][s]
    __hip_bfloat16* ub   = (__hip_bfloat16*)(ws + (4 << 20)); // 32 MiB fragment-native

    k_params<<<129, 256, 0, stream>>>(lna, bm, ldt, abar, a64, bbar);
    k_gemm<<<dim3(C4, B_), 256, 0, stream>>>(x, bbar, abar, ub, e64);
    k_scan<<<dim3(C4, B_), 256, 0, stream>>>(ub, e64, abar, a64, z0, out);
}

// Round 16
// 48.520 us; speedup vs baseline: 1.4066x; 1.4066x over previous
//
#include <hip/hip_runtime.h>
#include <hip/hip_bf16.h>

// Problem constants (S4Layer: T=4096, B=16, D=128, S=256)
#define T_  4096
#define B_  16
#define D_  128
#define S_  256
#define WND 64             // chunk length = GEMM t-tile
#define C4  (T_/WND)       // 64 chunks

using bf8   = __attribute__((ext_vector_type(8))) short;   // 8 bf16 (4 VGPRs)
using f32x4 = __attribute__((ext_vector_type(4))) float;   // MFMA acc

__device__ inline float bfbits(unsigned short h) {
    return __builtin_bit_cast(float, (unsigned)h << 16);
}
__device__ inline unsigned short bf16bits(float f) {
    return __hip_bfloat16_raw(__float2bfloat16(f)).x;
}

// ---------------- K1: parameters (hoisted, computed ONCE) -------------------
__global__ __launch_bounds__(256) void k_params(
        const float* __restrict__ lna, const float* __restrict__ bmat,
        const float* __restrict__ ldt,
        float* __restrict__ abar, float* __restrict__ a64,
        __hip_bfloat16* __restrict__ bbar) {
    if (blockIdx.x < 128) {
        int idx = blockIdx.x * 256 + threadIdx.x;   // (s,d)
        int s = idx >> 7;
        float la = fminf(fmaxf(lna[s], -8.f), 4.f);
        float ar = -expf(la);
        float lt = fminf(fmaxf(ldt[s], -8.f), 1.f);
        float dt = expf(lt);
        float xx = dt * ar;
        float ratio = (fabsf(xx) < 1e-6f) ? dt : (expm1f(xx) / ar);
        bbar[idx] = __float2bfloat16(ratio * bmat[idx]);
    } else {
        int s = threadIdx.x;
        float la = fminf(fmaxf(lna[s], -8.f), 4.f);
        float ar = -expf(la);
        float lt = fminf(fmaxf(ldt[s], -8.f), 1.f);
        float dt = expf(lt);
        float ab = expf(dt * ar);
        abar[s] = ab;
        float p = ab;
#pragma unroll
        for (int j = 0; j < 6; ++j) p *= p;     // a^64 by squaring
        a64[s] = p;
    }
}

// ---------------- K2: GEMM + e64 -> ub[b][t][s] (bf16) ---------------------
// Block (c,b): 64t x 256s tile (R8/R14 structure). bfrag loads hoisted above
// the barrier (overlap L2 latency with stage drain). e64 Horner from
// bf16-rounded acc; LDS-transposed epilogue emits ONE contiguous 32 KiB run.
__global__ __launch_bounds__(256, 4) void k_gemm(
        const float* __restrict__ x, const __hip_bfloat16* __restrict__ bbar,
        const float* __restrict__ abar,
        __hip_bfloat16* __restrict__ ub, float* __restrict__ e64) {
    const int c = blockIdx.x, b = blockIdx.y;
    __shared__ char LDS[WND * 512];    // 32 KiB: A-stage in [0,16K), then P
    const int tid = threadIdx.x, lane = tid & 63, w = tid >> 6;
    const int l15 = lane & 15, l4 = lane >> 4;

    // B fragments for ALL j, issued first (independent of LDS stage).
    bf8 bfrag[4][4];
#pragma unroll
    for (int j = 0; j < 4; ++j) {
        int s = w * 64 + j * 16 + l15;
#pragma unroll
        for (int kk = 0; kk < 4; ++kk)
            bfrag[j][kk] = *(const bf8*)((const short*)bbar + s * D_ + kk * 32 + l4 * 8);
    }

    // Stage A: rows t'=0..63 of batch b, fp32 -> bf16, swizzle ^((row&7)<<4)
#pragma unroll
    for (int k = 0; k < 8; ++k) {
        int idx = tid + k * 256;
        int row = idx >> 5, seg = idx & 31;
        float4 v = *(const float4*)(x + ((size_t)(c * WND + row) * B_ + b) * D_ + seg * 4);
        __hip_bfloat162 lo = __float22bfloat162_rn(make_float2(v.x, v.y));
        __hip_bfloat162 hi = __float22bfloat162_rn(make_float2(v.z, v.w));
        uint2 pk = { *(unsigned*)&lo, *(unsigned*)&hi };
        int off = (row * 256 + seg * 8) ^ ((row & 7) << 4);
        *(uint2*)(LDS + off) = pk;
    }
    __syncthreads();

    // MFMA: wave w owns s in [w*64,(w+1)*64); acc row = i*16 + l4*4 + r
    f32x4 acc[4][4] = {};
#pragma unroll
    for (int i = 0; i < 4; ++i) {
        bf8 af[4];
        int tr = i * 16 + l15;
#pragma unroll
        for (int kk = 0; kk < 4; ++kk) {
            int off = (tr * 256 + kk * 64 + l4 * 16) ^ ((tr & 7) << 4);
            af[kk] = *(const bf8*)(LDS + off);
        }
#pragma unroll
        for (int j = 0; j < 4; ++j)
#pragma unroll
            for (int kk = 0; kk < 4; ++kk)
                acc[i][j] = __builtin_amdgcn_mfma_f32_16x16x32_bf16(
                                af[kk], bfrag[j][kk], acc[i][j], 0, 0, 0);
    }
    __syncthreads();   // all A reads done; LDS becomes P[t'][s] bf16

    // e64 Horner (bf16-rounded, matches scan input) + P -> LDS (swizzled).
    // t' = i*16 + l4*4 + r ; weight a^(63-t') = a^(3-r)*a^(16(3-i))*a^(4(3-l4))
#pragma unroll
    for (int j = 0; j < 4; ++j) {
        int s = w * 64 + j * 16 + l15;
        float a  = abar[s];
        float a2 = a * a, a4 = a2 * a2, a8 = a4 * a4, a16 = a8 * a8;
        float lf = (l4 == 0) ? a8 * a4 : (l4 == 1) ? a8 : (l4 == 2) ? a4 : 1.f;
        float e = 0.f;
#pragma unroll
        for (int i = 0; i < 4; ++i) {
            unsigned short h0 = bf16bits(acc[i][j][0]);
            unsigned short h1 = bf16bits(acc[i][j][1]);
            unsigned short h2 = bf16bits(acc[i][j][2]);
            unsigned short h3 = bf16bits(acc[i][j][3]);
            float inner = bfbits(h0);
            inner = fmaf(inner, a, bfbits(h1));
            inner = fmaf(inner, a, bfbits(h2));
            inner = fmaf(inner, a, bfbits(h3));
            e = fmaf(e, a16, inner);
            int row0 = i * 16 + l4 * 4;            // ((row>>2)&3) == l4 here
            *(unsigned short*)(LDS + (((row0    ) * 512 + s * 2) ^ (l4 << 5))) = h0;
            *(unsigned short*)(LDS + (((row0 + 1) * 512 + s * 2) ^ (l4 << 5))) = h1;
            *(unsigned short*)(LDS + (((row0 + 2) * 512 + s * 2) ^ (l4 << 5))) = h2;
            *(unsigned short*)(LDS + (((row0 + 3) * 512 + s * 2) ^ (l4 << 5))) = h3;
        }
        e *= lf;
        e += __shfl_xor(e, 16);
        e += __shfl_xor(e, 32);
        if (l4 == 0) e64[((size_t)c * B_ + b) * S_ + s] = e;
    }
    __syncthreads();

    // Flat copy: ONE contiguous 32 KiB run -> ub[b][c*64 .. c*64+63][*]
    char* op = (char*)(ub + ((size_t)b * T_ + c * WND) * S_);
#pragma unroll
    for (int k = 0; k < 8; ++k) {
        int o = k * 4096 + tid * 16;
        int swz = (2 * k + (w >> 1)) & 3;          // = ((o>>11)&3)
        uint4 v = *(uint4*)(LDS + (o ^ (swz << 5)));
        *(uint4*)(op + o) = v;
    }
}

// ---------------- K3: fused carry + per-chunk scan + out, x2 s-vectorized --
// Block (c,g): wave w -> b = g*2 + (w>>1), s-half = (w&1); lane -> 2 s values.
// Carry-in via fixed-trip predicated Horner over e64 partials (L2-hot).
// Nontemporal out stores (write-once stream; keep ub/e64 in L2).
__global__ __launch_bounds__(256) void k_scan(
        const __hip_bfloat16* __restrict__ ub, const float* __restrict__ e64,
        const float* __restrict__ abar, const float* __restrict__ a64,
        const float* __restrict__ z0, float* __restrict__ out) {
    const int c = blockIdx.x, g = blockIdx.y;
    const int w = threadIdx.x >> 6, lane = threadIdx.x & 63;
    const int b = g * 2 + (w >> 1);
    const int s0 = (w & 1) * 128 + lane * 2;

    float2 a  = *(const float2*)(abar + s0);
    float2 aw = *(const float2*)(a64 + s0);
    float2 z  = *(const float2*)(z0 + b * S_ + s0);

    // carry: 64 fixed trips, batch-16 independent loads then predicated fma
#pragma unroll
    for (int cp0 = 0; cp0 < C4; cp0 += 16) {
        float2 ev[16];
#pragma unroll
        for (int k = 0; k < 16; ++k)
            ev[k] = *(const float2*)(e64 + ((size_t)(cp0 + k) * B_ + b) * S_ + s0);
#pragma unroll
        for (int k = 0; k < 16; ++k) {
            float zx = fmaf(aw.x, z.x, ev[k].x);
            float zy = fmaf(aw.y, z.y, ev[k].y);
            bool p = (cp0 + k) < c;
            z.x = p ? zx : z.x;
            z.y = p ? zy : z.y;
        }
    }

    // scan own chunk, coalesced; nontemporal stores
    const char* up = (const char*)(ub + ((size_t)b * T_ + c * WND) * S_ + s0);
    float* op = out + ((size_t)(c * WND) * B_ + b) * S_ + s0;
#pragma unroll 8
    for (int t = 0; t < WND; ++t) {
        ushort2 v = *(const ushort2*)up;           // 4 B/lane, 256 B/wave
        z.x = fmaf(a.x, z.x, bfbits(v.x));
        z.y = fmaf(a.y, z.y, bfbits(v.y));
        __builtin_nontemporal_store(z.x, op);
        __builtin_nontemporal_store(z.y, op + 1);
        up += S_ * 2;
        op += (size_t)B_ * S_;
    }
}

extern "C" void kernel_launch(void* const* d_in, const int* in_sizes, int n_in,
                              void* d_out, int out_size, void* d_ws, size_t ws_size,
                              hipStream_t stream) {
    const float* x   = (const float*)d_in[0];  // [T,B,D]
    const float* z0  = (const float*)d_in[1];  // [B,S]
    const float* lna = (const float*)d_in[2];  // [S]
    const float* bm  = (const float*)d_in[3];  // [S,D]
    const float* ldt = (const float*)d_in[4];  // [S]
    float* out = (float*)d_out;

    char* ws = (char*)d_ws;
    float*          abar = (float*)ws;                        // 1 KiB
    float*          a64  = (float*)(ws + 4096);               // 1 KiB
    __hip_bfloat16* bbar = (__hip_bfloat16*)(ws + 8192);      // 64 KiB
    float*          e64  = (float*)(ws + (128 << 10));        // 1 MiB [c][b][s]
    __hip_bfloat16* ub   = (__hip_bfloat16*)(ws + (4 << 20)); // 32 MiB [b][t][s]

    k_params<<<129, 256, 0, stream>>>(lna, bm, ldt, abar, a64, bbar);
    k_gemm<<<dim3(C4, B_), 256, 0, stream>>>(x, bbar, abar, ub, e64);
    k_scan<<<dim3(C4, B_ / 2), 256, 0, stream>>>(ub, e64, abar, a64, z0, out);
}